// Round 9
// baseline (1024.754 us; speedup 1.0000x reference)
//
#include <hip/hip_runtime.h>
#include <math.h>

// N=50000, F=256, H=256, C=40, E=800000; CURV=1, EPS=4e-3 -> maxnorm=0.996

typedef short bf16x8 __attribute__((ext_vector_type(8)));
typedef float f32x4 __attribute__((ext_vector_type(4)));

// pack two fp32 -> bf16x2 (round-half-up) : low short = a, high short = b
__device__ inline unsigned pack_bf16_hu(float a, float b) {
    unsigned ua = __float_as_uint(a) + 0x8000u;
    unsigned ub = __float_as_uint(b) + 0x8000u;
    return __builtin_amdgcn_perm(ub, ua, 0x07060302u);
}

__device__ inline unsigned short f2bf_rne(float x) {
    unsigned u = __float_as_uint(x);
    unsigned r = (u + 0x7fffu + ((u >> 16) & 1u)) >> 16;
    return (unsigned short)r;
}

// split (a,b) into hi bf16 pair + residual-lo bf16 pair (packed uints)
__device__ inline void split2(float a, float b, unsigned* hw, unsigned* lw) {
    unsigned ua = __float_as_uint(a) + 0x8000u;
    unsigned ub = __float_as_uint(b) + 0x8000u;
    *hw = __builtin_amdgcn_perm(ub, ua, 0x07060302u);
    float ra = a - __uint_as_float(ua & 0xFFFF0000u);
    float rb = b - __uint_as_float(ub & 0xFFFF0000u);
    unsigned va = __float_as_uint(ra) + 0x8000u;
    unsigned vb = __float_as_uint(rb) + 0x8000u;
    *lw = __builtin_amdgcn_perm(vb, va, 0x07060302u);
}

// ---------------- CSR build ----------------

__global__ void k_count(const int* __restrict__ dst, int* __restrict__ deg, int E) {
    int e = blockIdx.x * 256 + threadIdx.x;
    if (e < E) atomicAdd(&deg[dst[e]], 1);
}

__global__ __launch_bounds__(256) void k_scanA(const int* __restrict__ deg,
                                               int* __restrict__ offs,
                                               float* __restrict__ invc,
                                               int* __restrict__ bsum, int N) {
    __shared__ int wt[4];
    int tid = threadIdx.x, lane = tid & 63, wid = tid >> 6;
    int base = blockIdx.x * 1024 + tid * 4;
    int v[4];
    #pragma unroll
    for (int j = 0; j < 4; ++j) {
        int i = base + j;
        v[j] = (i < N) ? deg[i] : 0;
        if (i < N) invc[i] = 1.0f / (float)max(v[j], 1);
    }
    int t = v[0] + v[1] + v[2] + v[3];
    int s = t;
    #pragma unroll
    for (int d = 1; d < 64; d <<= 1) {
        int u = __shfl_up(s, d);
        if (lane >= d) s += u;
    }
    if (lane == 63) wt[wid] = s;
    __syncthreads();
    int wpre = 0, btot = 0;
    #pragma unroll
    for (int q = 0; q < 4; ++q) {
        int x = wt[q];
        btot += x;
        if (q < wid) wpre += x;
    }
    int run = wpre + s - t;
    #pragma unroll
    for (int j = 0; j < 4; ++j) {
        int i = base + j;
        if (i < N) offs[i] = run;
        run += v[j];
    }
    if (tid == 0) bsum[blockIdx.x] = btot;
}

__global__ __launch_bounds__(64) void k_scanB(int* __restrict__ bsum,
                                              int* __restrict__ offs, int N, int G) {
    int lane = threadIdx.x;
    int run = 0;
    for (int base = 0; base < G; base += 64) {
        int i = base + lane;
        int v = (i < G) ? bsum[i] : 0;
        int s = v;
        #pragma unroll
        for (int d = 1; d < 64; d <<= 1) {
            int u = __shfl_up(s, d);
            if (lane >= d) s += u;
        }
        int tot = __shfl(s, 63);
        if (i < G) bsum[i] = run + s - v;
        run += tot;
    }
    if (lane == 0) offs[N] = run;
}

__global__ __launch_bounds__(256) void k_scanC(int* __restrict__ offs,
                                               const int* __restrict__ bsum, int N) {
    int add = bsum[blockIdx.x];
    int base = blockIdx.x * 1024 + threadIdx.x * 4;
    #pragma unroll
    for (int j = 0; j < 4; ++j) {
        int i = base + j;
        if (i < N) offs[i] += add;
    }
}

__global__ void k_scatter(const int* __restrict__ src, const int* __restrict__ dst,
                          const int* __restrict__ offs, int* __restrict__ cursor,
                          int* __restrict__ ssrc, int E) {
    int e = blockIdx.x * 256 + threadIdx.x;
    if (e >= E) return;
    int d = dst[e];
    int pos = offs[d] + atomicAdd(&cursor[d], 1);
    ssrc[pos] = src[e];
}

// ---------------- weight prep ----------------

__global__ __launch_bounds__(256) void k_wsplit0(const float* __restrict__ Wl,
                                                 const float* __restrict__ Wr,
                                                 unsigned short* __restrict__ Wth,
                                                 unsigned short* __restrict__ Wtl) {
    int idx = blockIdx.x * 256 + threadIdx.x;   // < 512*256
    int n = idx >> 8, k = idx & 255;
    float v = (n < 256) ? Wl[k * 256 + n] : Wr[k * 256 + (n - 256)];
    unsigned short h = f2bf_rne(v);
    float hf = __uint_as_float(((unsigned)h) << 16);
    Wth[idx] = h;
    Wtl[idx] = f2bf_rne(v - hf);
}

__global__ __launch_bounds__(256) void k_wsplit1(const float* __restrict__ Wl,
                                                 const float* __restrict__ Wr,
                                                 unsigned short* __restrict__ Wth,
                                                 unsigned short* __restrict__ Wtl) {
    int idx = blockIdx.x * 256 + threadIdx.x;   // < 80*256
    if (idx >= 80 * 256) return;
    int n = idx >> 8, k = idx & 255;
    float v = (n < 40) ? Wl[k * 40 + n] : Wr[k * 40 + (n - 40)];
    unsigned short h = f2bf_rne(v);
    float hf = __uint_as_float(((unsigned)h) << 16);
    Wth[idx] = h;
    Wtl[idx] = f2bf_rne(v - hf);
}

// ---------------- gemm0 (merged, K-split staging): [Yl bf16 | Yr fp32] ----------------
// Waves 0-3 -> Yl cols 0..255, waves 4-7 -> Yr cols 256..511.
// X staged in two 128-wide K-halves -> LDS 34.8 KB -> 4 blocks/CU.

#define AROW2 136   // LDS row stride in shorts (128 + 8 pad)

__global__ __launch_bounds__(512, 8) void gemm0_mfma(const float* __restrict__ X,
                                                     const unsigned short* __restrict__ Bh,
                                                     const unsigned short* __restrict__ Bl,
                                                     unsigned short* __restrict__ Yl,
                                                     float* __restrict__ Yr, int N) {
    __shared__ __align__(16) unsigned short AhL[64 * AROW2];
    __shared__ __align__(16) unsigned short AlL[64 * AROW2];

    int tid = threadIdx.x;
    int lane = tid & 63;
    int w = __builtin_amdgcn_readfirstlane(tid >> 6);   // 0..7
    int ml = lane & 15, quad = lane >> 4;
    int m0 = blockIdx.x * 64;
    bool isYl = (w < 4);
    int wc = w & 3;

    auto stage = [&](int h) {
        #pragma unroll
        for (int c = 0; c < 4; ++c) {
            int idx = c * 512 + tid;        // float4 index in 64x32 float4 half-tile
            int row = idx >> 5;
            int col4 = (idx & 31) * 4;
            int gr = m0 + row;
            float4 v = make_float4(0.f, 0.f, 0.f, 0.f);
            if (gr < N) v = *(const float4*)&X[(size_t)gr * 256 + h * 128 + col4];
            unsigned h0, l0, h1, l1;
            split2(v.x, v.y, &h0, &l0);
            split2(v.z, v.w, &h1, &l1);
            *(uint2*)&AhL[row * AROW2 + col4] = make_uint2(h0, h1);
            *(uint2*)&AlL[row * AROW2 + col4] = make_uint2(l0, l1);
        }
    };

    f32x4 acc[4][4];
    #pragma unroll
    for (int a = 0; a < 4; ++a)
        #pragma unroll
        for (int b = 0; b < 4; ++b) acc[a][b] = (f32x4){0.f, 0.f, 0.f, 0.f};

    int bcol[4];
    #pragma unroll
    for (int nf = 0; nf < 4; ++nf)
        bcol[nf] = isYl ? (wc * 64 + (nf & 2) * 16 + 2 * ml + (nf & 1))
                        : (256 + wc * 64 + nf * 16 + ml);

    bf16x8 bh0[4], bl0[4], bh1[4], bl1[4];

    auto loadB = [&](int it, bf16x8* bh, bf16x8* bl) {
        int ko = it * 32 + quad * 8;
        #pragma unroll
        for (int nf = 0; nf < 4; ++nf) {
            size_t bo = (size_t)bcol[nf] * 256 + ko;
            bh[nf] = *(const bf16x8*)&Bh[bo];
            bl[nf] = *(const bf16x8*)&Bl[bo];
        }
    };

    stage(0);
    loadB(0, bh0, bl0);
    __syncthreads();

    #pragma unroll
    for (int g = 0; g < 8; ++g) {
        if (g == 4) {
            __syncthreads();   // all waves done reading half 0
            stage(1);
            __syncthreads();
        }
        bf16x8* bhc = (g & 1) ? bh1 : bh0;
        bf16x8* blc = (g & 1) ? bl1 : bl0;
        bf16x8* bhn = (g & 1) ? bh0 : bh1;
        bf16x8* bln = (g & 1) ? bl0 : bl1;
        if (g < 7) loadB(g + 1, bhn, bln);
        int koff = (g & 3) * 32 + quad * 8;
        bf16x8 ah[4], al[4];
        #pragma unroll
        for (int mf = 0; mf < 4; ++mf) {
            int ro = (mf * 16 + ml) * AROW2 + koff;
            ah[mf] = *(const bf16x8*)&AhL[ro];
            al[mf] = *(const bf16x8*)&AlL[ro];
        }
        #pragma unroll
        for (int nf = 0; nf < 4; ++nf)
            #pragma unroll
            for (int mf = 0; mf < 4; ++mf) {
                acc[mf][nf] = __builtin_amdgcn_mfma_f32_16x16x32_bf16(ah[mf], bhc[nf], acc[mf][nf], 0, 0, 0);
                acc[mf][nf] = __builtin_amdgcn_mfma_f32_16x16x32_bf16(ah[mf], blc[nf], acc[mf][nf], 0, 0, 0);
                acc[mf][nf] = __builtin_amdgcn_mfma_f32_16x16x32_bf16(al[mf], bhc[nf], acc[mf][nf], 0, 0, 0);
            }
    }

    if (isYl) {
        #pragma unroll
        for (int mf = 0; mf < 4; ++mf)
            #pragma unroll
            for (int r = 0; r < 4; ++r) {
                int row = m0 + mf * 16 + quad * 4 + r;
                if (row < N) {
                    unsigned p0 = pack_bf16_hu(acc[mf][0][r], acc[mf][1][r]);
                    unsigned p1 = pack_bf16_hu(acc[mf][2][r], acc[mf][3][r]);
                    *(unsigned*)&Yl[(size_t)row * 256 + wc * 64 + 2 * ml] = p0;
                    *(unsigned*)&Yl[(size_t)row * 256 + wc * 64 + 32 + 2 * ml] = p1;
                }
            }
    } else {
        #pragma unroll
        for (int mf = 0; mf < 4; ++mf)
            #pragma unroll
            for (int r = 0; r < 4; ++r) {
                int row = m0 + mf * 16 + quad * 4 + r;
                if (row < N) {
                    #pragma unroll
                    for (int nf = 0; nf < 4; ++nf)
                        Yr[(size_t)row * 256 + wc * 64 + nf * 16 + ml] = acc[mf][nf][r];
                }
            }
    }
}

// ---------------- combine0: h = relu(agg(Yl)/cnt + bl0 + Yr) -> Hf fragment layout ----------------

__global__ __launch_bounds__(256) void combine0(const unsigned short* __restrict__ Yl,
                                                const float* __restrict__ Yr,
                                                const int* __restrict__ offs,
                                                const int* __restrict__ ssrc,
                                                const float* __restrict__ invc,
                                                const float* __restrict__ bl0,
                                                unsigned short* __restrict__ Hh,
                                                unsigned short* __restrict__ Hl, int N) {
    int wv = threadIdx.x >> 6, lane = threadIdx.x & 63;
    int n = blockIdx.x * 4 + wv;
    if (n >= N) return;
    int e0 = offs[n], e1 = offs[n + 1];
    float4 acc = make_float4(0.f, 0.f, 0.f, 0.f);
    int e = e0;
    for (; e + 3 < e1; e += 4) {
        int s0 = ssrc[e], s1 = ssrc[e + 1], s2 = ssrc[e + 2], s3 = ssrc[e + 3];
        uint2 p = *(const uint2*)&Yl[(size_t)s0 * 256 + lane * 4];
        uint2 q = *(const uint2*)&Yl[(size_t)s1 * 256 + lane * 4];
        uint2 u = *(const uint2*)&Yl[(size_t)s2 * 256 + lane * 4];
        uint2 t = *(const uint2*)&Yl[(size_t)s3 * 256 + lane * 4];
        acc.x += (__uint_as_float(p.x << 16) + __uint_as_float(q.x << 16)) +
                 (__uint_as_float(u.x << 16) + __uint_as_float(t.x << 16));
        acc.y += (__uint_as_float(p.x & 0xFFFF0000u) + __uint_as_float(q.x & 0xFFFF0000u)) +
                 (__uint_as_float(u.x & 0xFFFF0000u) + __uint_as_float(t.x & 0xFFFF0000u));
        acc.z += (__uint_as_float(p.y << 16) + __uint_as_float(q.y << 16)) +
                 (__uint_as_float(u.y << 16) + __uint_as_float(t.y << 16));
        acc.w += (__uint_as_float(p.y & 0xFFFF0000u) + __uint_as_float(q.y & 0xFFFF0000u)) +
                 (__uint_as_float(u.y & 0xFFFF0000u) + __uint_as_float(t.y & 0xFFFF0000u));
    }
    for (; e < e1; ++e) {
        int s0 = ssrc[e];
        uint2 p = *(const uint2*)&Yl[(size_t)s0 * 256 + lane * 4];
        acc.x += __uint_as_float(p.x << 16);
        acc.y += __uint_as_float(p.x & 0xFFFF0000u);
        acc.z += __uint_as_float(p.y << 16);
        acc.w += __uint_as_float(p.y & 0xFFFF0000u);
    }
    float ic = invc[n];
    float4 b = *(const float4*)&bl0[lane * 4];
    float4 yr = *(const float4*)&Yr[(size_t)n * 256 + lane * 4];
    float hx = fmaxf(acc.x * ic + b.x + yr.x, 0.f);
    float hy = fmaxf(acc.y * ic + b.y + yr.y, 0.f);
    float hz = fmaxf(acc.z * ic + b.z + yr.z, 0.f);
    float hw = fmaxf(acc.w * ic + b.w + yr.w, 0.f);
    unsigned h0, h1, l0, l1;
    split2(hx, hy, &h0, &l0);
    split2(hz, hw, &h1, &l1);
    int t2 = n >> 4, r = n & 15;
    int kc = lane >> 3, q = (lane >> 1) & 3, ee = (lane & 1) * 4;
    size_t offH = (size_t)t2 * 4096 + kc * 512 + q * 128 + r * 8 + ee;
    *(uint2*)&Hh[offH] = make_uint2(h0, h1);
    *(uint2*)&Hl[offH] = make_uint2(l0, l1);
}

// ---------------- gemm1: [Zl bf16 | Zr fp32] = H @ Wt1^T; one wave per 16-node tile ----------------

__global__ __launch_bounds__(256) void gemm1_mfma(const unsigned short* __restrict__ Hh,
                                                  const unsigned short* __restrict__ Hl,
                                                  const unsigned short* __restrict__ Bh,
                                                  const unsigned short* __restrict__ Bl,
                                                  unsigned short* __restrict__ Zl,
                                                  float* __restrict__ Zr, int N, int numTiles) {
    int tid = threadIdx.x;
    int lane = tid & 63;
    int w = __builtin_amdgcn_readfirstlane(tid >> 6);
    int ml = lane & 15, quad = lane >> 4;
    int t = blockIdx.x * 4 + w;
    if (t >= numTiles) return;

    const unsigned short* ahp = Hh + (size_t)t * 4096 + quad * 128 + ml * 8;
    const unsigned short* alp = Hl + (size_t)t * 4096 + quad * 128 + ml * 8;

    f32x4 acc[5];
    #pragma unroll
    for (int b = 0; b < 5; ++b) acc[b] = (f32x4){0.f, 0.f, 0.f, 0.f};

    #pragma unroll
    for (int kc = 0; kc < 8; ++kc) {
        bf16x8 ah = *(const bf16x8*)&ahp[kc * 512];
        bf16x8 al = *(const bf16x8*)&alp[kc * 512];
        int ko = kc * 32 + quad * 8;
        #pragma unroll
        for (int nf = 0; nf < 5; ++nf) {
            size_t bo = (size_t)(nf * 16 + ml) * 256 + ko;
            bf16x8 bh = *(const bf16x8*)&Bh[bo];
            bf16x8 bl = *(const bf16x8*)&Bl[bo];
            acc[nf] = __builtin_amdgcn_mfma_f32_16x16x32_bf16(ah, bh, acc[nf], 0, 0, 0);
            acc[nf] = __builtin_amdgcn_mfma_f32_16x16x32_bf16(ah, bl, acc[nf], 0, 0, 0);
            acc[nf] = __builtin_amdgcn_mfma_f32_16x16x32_bf16(al, bh, acc[nf], 0, 0, 0);
        }
    }
    #pragma unroll
    for (int r = 0; r < 4; ++r) {
        int n = t * 16 + quad * 4 + r;
        if (n < N) {
            #pragma unroll
            for (int nf = 0; nf < 5; ++nf) {
                int col = nf * 16 + ml;
                if (col < 40) Zl[(size_t)n * 40 + col] = f2bf_rne(acc[nf][r]);
                else Zr[(size_t)n * 40 + (col - 40)] = acc[nf][r];
            }
        }
    }
}

// ---------------- combine1: bf16 Zl gather ----------------

__global__ __launch_bounds__(256) void combine1(const unsigned short* __restrict__ Zl,
                                                const float* __restrict__ Zr,
                                                const int* __restrict__ offs,
                                                const int* __restrict__ ssrc,
                                                const float* __restrict__ invc,
                                                const float* __restrict__ bl1,
                                                float* __restrict__ H2, int N) {
    int wv = threadIdx.x >> 6, lane = threadIdx.x & 63;
    int n = blockIdx.x * 4 + wv;
    if (n >= N) return;
    if (lane >= 40) return;
    int e0 = offs[n], e1 = offs[n + 1];
    float acc = 0.f;
    int e = e0;
    for (; e + 1 < e1; e += 2) {
        int s0 = ssrc[e], s1 = ssrc[e + 1];
        unsigned a = Zl[(size_t)s0 * 40 + lane];
        unsigned b = Zl[(size_t)s1 * 40 + lane];
        acc += __uint_as_float(a << 16) + __uint_as_float(b << 16);
    }
    if (e < e1) {
        unsigned a = Zl[(size_t)ssrc[e] * 40 + lane];
        acc += __uint_as_float(a << 16);
    }
    float v = acc * invc[n] + bl1[lane] + Zr[(size_t)n * 40 + lane];
    H2[(size_t)n * 40 + lane] = v;
}

// ---------------- W_lin pre-convert: Wb[col][k'] bf16, k' = i*48+j, K'=2304 ----------------

__global__ __launch_bounds__(256) void k_wprep(const float* __restrict__ W,
                                               unsigned short* __restrict__ Wb) {
    int idx = blockIdx.x * 256 + threadIdx.x;   // < 48*2304
    if (idx >= 48 * 2304) return;
    int col = idx / 2304;
    int kp = idx - col * 2304;
    int i = kp / 48;
    int j = kp - i * 48;
    float v = 0.f;
    if (col < 40 && i < 40 && j < 40) v = W[((size_t)(i * 40 + j)) * 40 + col];
    Wb[idx] = f2bf_rne(v);
}

// ---------------- k_final_mfma v2 ----------------

__global__ __launch_bounds__(256) void k_final_mfma(const float* __restrict__ H2,
                                                    const unsigned short* __restrict__ Wb,
                                                    const float* __restrict__ blin,
                                                    float* __restrict__ out, int N) {
    __shared__ float q_lds[64 * 52];

    int tid = threadIdx.x;
    int m0 = blockIdx.x * 64;
    int lane = tid & 63;
    int w = __builtin_amdgcn_readfirstlane(tid >> 6);
    int ml = lane & 15;
    int quad = lane >> 4;
    int row = w * 16 + ml;
    int gn = m0 + row;

    float g[40];
    float s2 = 0.f;
    #pragma unroll
    for (int q4 = 0; q4 < 10; ++q4) {
        float4 v = make_float4(0.f, 0.f, 0.f, 0.f);
        if (gn < N) v = *(const float4*)&H2[(size_t)gn * 40 + q4 * 4];
        g[q4 * 4 + 0] = v.x; g[q4 * 4 + 1] = v.y;
        g[q4 * 4 + 2] = v.z; g[q4 * 4 + 3] = v.w;
        s2 += v.x * v.x + v.y * v.y + v.z * v.z + v.w * v.w;
    }
    float aln = atanhf(fminf(fmaxf(s2, 1e-15f), 0.996f)) / fmaxf(s2, 1e-30f);

    if (quad == 0) {
        float* qw = &q_lds[row * 52];
        #pragma unroll
        for (int j4 = 0; j4 < 10; ++j4)
            *(float4*)&qw[j4 * 4] = make_float4(g[j4 * 4], g[j4 * 4 + 1],
                                                g[j4 * 4 + 2], g[j4 * 4 + 3]);
        *(float4*)&qw[40] = make_float4(0.f, 0.f, 0.f, 0.f);
        *(float4*)&qw[44] = make_float4(0.f, 0.f, 0.f, 0.f);
    }
    __syncthreads();

    const float* qrow = &q_lds[row * 52];
    int jb0 = quad * 8;
    int jb1 = (quad < 2) ? (32 + quad * 8) : (quad * 8 - 16);
    int jb2 = 16 + quad * 8;
    int ih = quad >> 1;

    f32x4 acc[3];
    #pragma unroll
    for (int c = 0; c < 3; ++c) acc[c] = (f32x4){0.f, 0.f, 0.f, 0.f};

    const unsigned short* bw = Wb + (size_t)ml * 2304 + quad * 8;

    #pragma unroll
    for (int c = 0; c < 20; ++c) {
        const int kb = c * 96;
        {
            float gi = qrow[2 * c];
            float4 ga = *(const float4*)&qrow[jb0];
            float4 gb = *(const float4*)&qrow[jb0 + 4];
            union { unsigned u[4]; bf16x8 v; } A;
            A.u[0] = pack_bf16_hu(gi * ga.x, gi * ga.y);
            A.u[1] = pack_bf16_hu(gi * ga.z, gi * ga.w);
            A.u[2] = pack_bf16_hu(gi * gb.x, gi * gb.y);
            A.u[3] = pack_bf16_hu(gi * gb.z, gi * gb.w);
            #pragma unroll
            for (int cf = 0; cf < 3; ++cf) {
                bf16x8 bf = *(const bf16x8*)&bw[(size_t)cf * 16 * 2304 + kb];
                acc[cf] = __builtin_amdgcn_mfma_f32_16x16x32_bf16(A.v, bf, acc[cf], 0, 0, 0);
            }
        }
        {
            float gi = qrow[2 * c + ih];
            float4 ga = *(const float4*)&qrow[jb1];
            float4 gb = *(const float4*)&qrow[jb1 + 4];
            union { unsigned u[4]; bf16x8 v; } A;
            A.u[0] = pack_bf16_hu(gi * ga.x, gi * ga.y);
            A.u[1] = pack_bf16_hu(gi * ga.z, gi * ga.w);
            A.u[2] = pack_bf16_hu(gi * gb.x, gi * gb.y);
            A.u[3] = pack_bf16_hu(gi * gb.z, gi * gb.w);
            #pragma unroll
            for (int cf = 0; cf < 3; ++cf) {
                bf16x8 bf = *(const bf16x8*)&bw[(size_t)cf * 16 * 2304 + kb + 32];
                acc[cf] = __builtin_amdgcn_mfma_f32_16x16x32_bf16(A.v, bf, acc[cf], 0, 0, 0);
            }
        }
        {
            float gi = qrow[2 * c + 1];
            float4 ga = *(const float4*)&qrow[jb2];
            float4 gb = *(const float4*)&qrow[jb2 + 4];
            union { unsigned u[4]; bf16x8 v; } A;
            A.u[0] = pack_bf16_hu(gi * ga.x, gi * ga.y);
            A.u[1] = pack_bf16_hu(gi * ga.z, gi * ga.w);
            A.u[2] = pack_bf16_hu(gi * gb.x, gi * gb.y);
            A.u[3] = pack_bf16_hu(gi * gb.z, gi * gb.w);
            #pragma unroll
            for (int cf = 0; cf < 3; ++cf) {
                bf16x8 bf = *(const bf16x8*)&bw[(size_t)cf * 16 * 2304 + kb + 64];
                acc[cf] = __builtin_amdgcn_mfma_f32_16x16x32_bf16(A.v, bf, acc[cf], 0, 0, 0);
            }
        }
    }

    float bcol[3];
    #pragma unroll
    for (int c = 0; c < 3; ++c) {
        int col = c * 16 + ml;
        bcol[c] = (col < 40) ? blin[col] : 0.f;
    }
    bool v2 = (ml < 8);

    #pragma unroll
    for (int r = 0; r < 4; ++r) {
        int nloc = w * 16 + quad * 4 + r;
        float al = __shfl(aln, quad * 4 + r);
        float u0 = al * acc[0][r] + bcol[0];
        float u1 = al * acc[1][r] + bcol[1];
        float u2 = v2 ? (al * acc[2][r] + bcol[2]) : 0.f;
        float un2 = u0 * u0 + u1 * u1 + u2 * u2;
        #pragma unroll
        for (int m = 1; m < 16; m <<= 1) un2 += __shfl_xor(un2, m);
        float un = fmaxf(sqrtf(un2), 1e-15f);
        float tnh = tanhf(un);
        float gma = tnh / un;
        float ps = (tnh > 0.996f) ? (0.996f / tnh) : 1.0f;
        float s = gma * ps;
        float l0 = s * u0, l1 = s * u1, l2 = s * u2;
        float mx = fmaxf(l0, l1);
        if (v2) mx = fmaxf(mx, l2);
        #pragma unroll
        for (int m = 1; m < 16; m <<= 1) mx = fmaxf(mx, __shfl_xor(mx, m));
        float se = expf(l0 - mx) + expf(l1 - mx) + (v2 ? expf(l2 - mx) : 0.f);
        #pragma unroll
        for (int m = 1; m < 16; m <<= 1) se += __shfl_xor(se, m);
        float lse = logf(se);
        int go = m0 + nloc;
        if (go < N) {
            out[(size_t)go * 40 + ml] = l0 - mx - lse;
            out[(size_t)go * 40 + 16 + ml] = l1 - mx - lse;
            if (v2) out[(size_t)go * 40 + 32 + ml] = l2 - mx - lse;
        }
    }
}

// ---------------- launch ----------------

extern "C" void kernel_launch(void* const* d_in, const int* in_sizes, int n_in,
                              void* d_out, int out_size, void* d_ws, size_t ws_size,
                              hipStream_t stream) {
    const float* x    = (const float*)d_in[0];
    const int*   ei   = (const int*)d_in[1];
    const float* Wl0  = (const float*)d_in[2];
    const float* bl0  = (const float*)d_in[3];
    const float* Wr0  = (const float*)d_in[4];
    const float* Wl1  = (const float*)d_in[5];
    const float* bl1  = (const float*)d_in[6];
    const float* Wr1  = (const float*)d_in[7];
    const float* Wlin = (const float*)d_in[8];
    const float* blin = (const float*)d_in[9];
    int N = in_sizes[0] / 256;
    int E = in_sizes[1] / 2;
    const int* src = ei;
    const int* dst = ei + E;
    int numTiles = (N + 15) / 16;

    char* ws = (char*)d_ws;
    size_t off = 0;
    auto carve = [&](size_t bytes) -> char* {
        char* p = ws + off;
        off = (off + bytes + 255) & ~(size_t)255;
        return p;
    };
    int*   deg    = (int*)carve((size_t)N * 4);
    int*   cursor = (int*)carve((size_t)N * 4);
    int*   offs   = (int*)carve((size_t)(N + 1) * 4);
    float* invc   = (float*)carve((size_t)N * 4);
    int*   bsum   = (int*)carve(1024);
    int*   ssrc   = (int*)carve((size_t)E * 4);
    unsigned short* Yl = (unsigned short*)carve((size_t)N * 256 * 2);
    float* Yr     = (float*)carve((size_t)N * 256 * 4);
    unsigned short* Hh = (unsigned short*)carve((size_t)numTiles * 4096 * 2);
    unsigned short* Hl = (unsigned short*)carve((size_t)numTiles * 4096 * 2);
    unsigned short* Zl = (unsigned short*)carve((size_t)N * 40 * 2);
    float* Zr     = (float*)carve((size_t)N * 40 * 4);
    float* H2     = (float*)carve((size_t)N * 40 * 4);
    // Wb (48*2304 bf16 = 221 KB) aliases Yr (dead after combine0)
    unsigned short* Wb = (unsigned short*)Yr;
    // split weights (606 KB) alias H2 (written only at combine1, after gemm1)
    unsigned short* Wth  = (unsigned short*)H2;
    unsigned short* Wtl  = Wth + 512 * 256;
    unsigned short* Wt1h = Wtl + 512 * 256;
    unsigned short* Wt1l = Wt1h + 80 * 256;

    int G = (N + 1023) / 1024;

    hipMemsetAsync(deg, 0, (size_t)N * 4, stream);
    hipMemsetAsync(cursor, 0, (size_t)N * 4, stream);

    k_count<<<(E + 255) / 256, 256, 0, stream>>>(dst, deg, E);
    k_scanA<<<G, 256, 0, stream>>>(deg, offs, invc, bsum, N);
    k_scanB<<<1, 64, 0, stream>>>(bsum, offs, N, G);
    k_scanC<<<G, 256, 0, stream>>>(offs, bsum, N);
    k_scatter<<<(E + 255) / 256, 256, 0, stream>>>(src, dst, offs, cursor, ssrc, E);
    k_wsplit0<<<(512 * 256) / 256, 256, 0, stream>>>(Wl0, Wr0, Wth, Wtl);
    k_wsplit1<<<(80 * 256 + 255) / 256, 256, 0, stream>>>(Wl1, Wr1, Wt1h, Wt1l);
    gemm0_mfma<<<(N + 63) / 64, 512, 0, stream>>>(x, Wth, Wtl, Yl, Yr, N);
    combine0<<<(N + 3) / 4, 256, 0, stream>>>(Yl, Yr, offs, ssrc, invc, bl0, Hh, Hl, N);
    k_wprep<<<(48 * 2304) / 256, 256, 0, stream>>>(Wlin, Wb);   // after combine0 (Yr alias)
    gemm1_mfma<<<(numTiles + 3) / 4, 256, 0, stream>>>(Hh, Hl, Wt1h, Wt1l, Zl, Zr, N, numTiles);
    combine1<<<(N + 3) / 4, 256, 0, stream>>>(Zl, Zr, offs, ssrc, invc, bl1, H2, N);
    k_final_mfma<<<(N + 63) / 64, 256, 0, stream>>>(H2, Wb, blin, (float*)d_out, N);
}

// Round 10
// 523.631 us; speedup vs baseline: 1.9570x; 1.9570x over previous
//
#include <hip/hip_runtime.h>
#include <math.h>

// N=50000, F=256, H=256, C=40, E=800000; CURV=1, EPS=4e-3 -> maxnorm=0.996

typedef short bf16x8 __attribute__((ext_vector_type(8)));
typedef float f32x4 __attribute__((ext_vector_type(4)));

// pack two fp32 -> bf16x2 (round-half-up) : low short = a, high short = b
__device__ inline unsigned pack_bf16_hu(float a, float b) {
    unsigned ua = __float_as_uint(a) + 0x8000u;
    unsigned ub = __float_as_uint(b) + 0x8000u;
    return __builtin_amdgcn_perm(ub, ua, 0x07060302u);
}

__device__ inline unsigned short f2bf_rne(float x) {
    unsigned u = __float_as_uint(x);
    unsigned r = (u + 0x7fffu + ((u >> 16) & 1u)) >> 16;
    return (unsigned short)r;
}

// split (a,b) into hi bf16 pair + residual-lo bf16 pair (packed uints)
__device__ inline void split2(float a, float b, unsigned* hw, unsigned* lw) {
    unsigned ua = __float_as_uint(a) + 0x8000u;
    unsigned ub = __float_as_uint(b) + 0x8000u;
    *hw = __builtin_amdgcn_perm(ub, ua, 0x07060302u);
    float ra = a - __uint_as_float(ua & 0xFFFF0000u);
    float rb = b - __uint_as_float(ub & 0xFFFF0000u);
    unsigned va = __float_as_uint(ra) + 0x8000u;
    unsigned vb = __float_as_uint(rb) + 0x8000u;
    *lw = __builtin_amdgcn_perm(vb, va, 0x07060302u);
}

// ---------------- CSR build ----------------

__global__ void k_count(const int* __restrict__ dst, int* __restrict__ deg, int E) {
    int e = blockIdx.x * 256 + threadIdx.x;
    if (e < E) atomicAdd(&deg[dst[e]], 1);
}

__global__ __launch_bounds__(256) void k_scanA(const int* __restrict__ deg,
                                               int* __restrict__ offs,
                                               float* __restrict__ invc,
                                               int* __restrict__ bsum, int N) {
    __shared__ int wt[4];
    int tid = threadIdx.x, lane = tid & 63, wid = tid >> 6;
    int base = blockIdx.x * 1024 + tid * 4;
    int v[4];
    #pragma unroll
    for (int j = 0; j < 4; ++j) {
        int i = base + j;
        v[j] = (i < N) ? deg[i] : 0;
        if (i < N) invc[i] = 1.0f / (float)max(v[j], 1);
    }
    int t = v[0] + v[1] + v[2] + v[3];
    int s = t;
    #pragma unroll
    for (int d = 1; d < 64; d <<= 1) {
        int u = __shfl_up(s, d);
        if (lane >= d) s += u;
    }
    if (lane == 63) wt[wid] = s;
    __syncthreads();
    int wpre = 0, btot = 0;
    #pragma unroll
    for (int q = 0; q < 4; ++q) {
        int x = wt[q];
        btot += x;
        if (q < wid) wpre += x;
    }
    int run = wpre + s - t;
    #pragma unroll
    for (int j = 0; j < 4; ++j) {
        int i = base + j;
        if (i < N) offs[i] = run;
        run += v[j];
    }
    if (tid == 0) bsum[blockIdx.x] = btot;
}

__global__ __launch_bounds__(64) void k_scanB(int* __restrict__ bsum,
                                              int* __restrict__ offs, int N, int G) {
    int lane = threadIdx.x;
    int run = 0;
    for (int base = 0; base < G; base += 64) {
        int i = base + lane;
        int v = (i < G) ? bsum[i] : 0;
        int s = v;
        #pragma unroll
        for (int d = 1; d < 64; d <<= 1) {
            int u = __shfl_up(s, d);
            if (lane >= d) s += u;
        }
        int tot = __shfl(s, 63);
        if (i < G) bsum[i] = run + s - v;
        run += tot;
    }
    if (lane == 0) offs[N] = run;
}

__global__ __launch_bounds__(256) void k_scanC(int* __restrict__ offs,
                                               const int* __restrict__ bsum, int N) {
    int add = bsum[blockIdx.x];
    int base = blockIdx.x * 1024 + threadIdx.x * 4;
    #pragma unroll
    for (int j = 0; j < 4; ++j) {
        int i = base + j;
        if (i < N) offs[i] += add;
    }
}

__global__ void k_scatter(const int* __restrict__ src, const int* __restrict__ dst,
                          const int* __restrict__ offs, int* __restrict__ cursor,
                          int* __restrict__ ssrc, int E) {
    int e = blockIdx.x * 256 + threadIdx.x;
    if (e >= E) return;
    int d = dst[e];
    int pos = offs[d] + atomicAdd(&cursor[d], 1);
    ssrc[pos] = src[e];
}

// ---------------- weight prep ----------------

__global__ __launch_bounds__(256) void k_wsplit0(const float* __restrict__ Wl,
                                                 const float* __restrict__ Wr,
                                                 unsigned short* __restrict__ Wth,
                                                 unsigned short* __restrict__ Wtl) {
    int idx = blockIdx.x * 256 + threadIdx.x;   // < 512*256
    int n = idx >> 8, k = idx & 255;
    float v = (n < 256) ? Wl[k * 256 + n] : Wr[k * 256 + (n - 256)];
    unsigned short h = f2bf_rne(v);
    float hf = __uint_as_float(((unsigned)h) << 16);
    Wth[idx] = h;
    Wtl[idx] = f2bf_rne(v - hf);
}

__global__ __launch_bounds__(256) void k_wsplit1(const float* __restrict__ Wl,
                                                 const float* __restrict__ Wr,
                                                 unsigned short* __restrict__ Wth,
                                                 unsigned short* __restrict__ Wtl) {
    int idx = blockIdx.x * 256 + threadIdx.x;   // < 80*256
    if (idx >= 80 * 256) return;
    int n = idx >> 8, k = idx & 255;
    float v = (n < 40) ? Wl[k * 40 + n] : Wr[k * 40 + (n - 40)];
    unsigned short h = f2bf_rne(v);
    float hf = __uint_as_float(((unsigned)h) << 16);
    Wth[idx] = h;
    Wtl[idx] = f2bf_rne(v - hf);
}

// ---------------- gemm0 (merged, K-split staging): [Yl bf16 | Yr fp32] ----------------
// Waves 0-3 -> Yl cols 0..255, waves 4-7 -> Yr cols 256..511.
// X staged in two 128-wide K-halves -> LDS 34.8 KB -> ~3 blocks/CU.
// NO min-waves launch bound (round-9 lesson: (512,8) forced VGPR=32 -> 1.3 GB spill).

#define AROW2 136   // LDS row stride in shorts (128 + 8 pad)

__global__ __launch_bounds__(512) void gemm0_mfma(const float* __restrict__ X,
                                                  const unsigned short* __restrict__ Bh,
                                                  const unsigned short* __restrict__ Bl,
                                                  unsigned short* __restrict__ Yl,
                                                  float* __restrict__ Yr, int N) {
    __shared__ __align__(16) unsigned short AhL[64 * AROW2];
    __shared__ __align__(16) unsigned short AlL[64 * AROW2];

    int tid = threadIdx.x;
    int lane = tid & 63;
    int w = __builtin_amdgcn_readfirstlane(tid >> 6);   // 0..7
    int ml = lane & 15, quad = lane >> 4;
    int m0 = blockIdx.x * 64;
    bool isYl = (w < 4);
    int wc = w & 3;

    auto stage = [&](int h) {
        #pragma unroll
        for (int c = 0; c < 4; ++c) {
            int idx = c * 512 + tid;        // float4 index in 64x32 float4 half-tile
            int row = idx >> 5;
            int col4 = (idx & 31) * 4;
            int gr = m0 + row;
            float4 v = make_float4(0.f, 0.f, 0.f, 0.f);
            if (gr < N) v = *(const float4*)&X[(size_t)gr * 256 + h * 128 + col4];
            unsigned h0, l0, h1, l1;
            split2(v.x, v.y, &h0, &l0);
            split2(v.z, v.w, &h1, &l1);
            *(uint2*)&AhL[row * AROW2 + col4] = make_uint2(h0, h1);
            *(uint2*)&AlL[row * AROW2 + col4] = make_uint2(l0, l1);
        }
    };

    f32x4 acc[4][4];
    #pragma unroll
    for (int a = 0; a < 4; ++a)
        #pragma unroll
        for (int b = 0; b < 4; ++b) acc[a][b] = (f32x4){0.f, 0.f, 0.f, 0.f};

    int bcol[4];
    #pragma unroll
    for (int nf = 0; nf < 4; ++nf)
        bcol[nf] = isYl ? (wc * 64 + (nf & 2) * 16 + 2 * ml + (nf & 1))
                        : (256 + wc * 64 + nf * 16 + ml);

    bf16x8 bh0[4], bl0[4], bh1[4], bl1[4];

    auto loadB = [&](int it, bf16x8* bh, bf16x8* bl) {
        int ko = it * 32 + quad * 8;
        #pragma unroll
        for (int nf = 0; nf < 4; ++nf) {
            size_t bo = (size_t)bcol[nf] * 256 + ko;
            bh[nf] = *(const bf16x8*)&Bh[bo];
            bl[nf] = *(const bf16x8*)&Bl[bo];
        }
    };

    stage(0);
    loadB(0, bh0, bl0);
    __syncthreads();

    #pragma unroll
    for (int g = 0; g < 8; ++g) {
        if (g == 4) {
            __syncthreads();   // all waves done reading half 0
            stage(1);
            __syncthreads();
        }
        bf16x8* bhc = (g & 1) ? bh1 : bh0;
        bf16x8* blc = (g & 1) ? bl1 : bl0;
        bf16x8* bhn = (g & 1) ? bh0 : bh1;
        bf16x8* bln = (g & 1) ? bl0 : bl1;
        if (g < 7) loadB(g + 1, bhn, bln);
        int koff = (g & 3) * 32 + quad * 8;
        bf16x8 ah[4], al[4];
        #pragma unroll
        for (int mf = 0; mf < 4; ++mf) {
            int ro = (mf * 16 + ml) * AROW2 + koff;
            ah[mf] = *(const bf16x8*)&AhL[ro];
            al[mf] = *(const bf16x8*)&AlL[ro];
        }
        #pragma unroll
        for (int nf = 0; nf < 4; ++nf)
            #pragma unroll
            for (int mf = 0; mf < 4; ++mf) {
                acc[mf][nf] = __builtin_amdgcn_mfma_f32_16x16x32_bf16(ah[mf], bhc[nf], acc[mf][nf], 0, 0, 0);
                acc[mf][nf] = __builtin_amdgcn_mfma_f32_16x16x32_bf16(ah[mf], blc[nf], acc[mf][nf], 0, 0, 0);
                acc[mf][nf] = __builtin_amdgcn_mfma_f32_16x16x32_bf16(al[mf], bhc[nf], acc[mf][nf], 0, 0, 0);
            }
    }

    if (isYl) {
        #pragma unroll
        for (int mf = 0; mf < 4; ++mf)
            #pragma unroll
            for (int r = 0; r < 4; ++r) {
                int row = m0 + mf * 16 + quad * 4 + r;
                if (row < N) {
                    unsigned p0 = pack_bf16_hu(acc[mf][0][r], acc[mf][1][r]);
                    unsigned p1 = pack_bf16_hu(acc[mf][2][r], acc[mf][3][r]);
                    *(unsigned*)&Yl[(size_t)row * 256 + wc * 64 + 2 * ml] = p0;
                    *(unsigned*)&Yl[(size_t)row * 256 + wc * 64 + 32 + 2 * ml] = p1;
                }
            }
    } else {
        #pragma unroll
        for (int mf = 0; mf < 4; ++mf)
            #pragma unroll
            for (int r = 0; r < 4; ++r) {
                int row = m0 + mf * 16 + quad * 4 + r;
                if (row < N) {
                    #pragma unroll
                    for (int nf = 0; nf < 4; ++nf)
                        Yr[(size_t)row * 256 + wc * 64 + nf * 16 + ml] = acc[mf][nf][r];
                }
            }
    }
}

// ---------------- combine0: h = relu(agg(Yl)/cnt + bl0 + Yr) -> Hf fragment layout ----------------

__global__ __launch_bounds__(256) void combine0(const unsigned short* __restrict__ Yl,
                                                const float* __restrict__ Yr,
                                                const int* __restrict__ offs,
                                                const int* __restrict__ ssrc,
                                                const float* __restrict__ invc,
                                                const float* __restrict__ bl0,
                                                unsigned short* __restrict__ Hh,
                                                unsigned short* __restrict__ Hl, int N) {
    int wv = threadIdx.x >> 6, lane = threadIdx.x & 63;
    int n = blockIdx.x * 4 + wv;
    if (n >= N) return;
    int e0 = offs[n], e1 = offs[n + 1];
    float4 acc = make_float4(0.f, 0.f, 0.f, 0.f);
    int e = e0;
    for (; e + 3 < e1; e += 4) {
        int s0 = ssrc[e], s1 = ssrc[e + 1], s2 = ssrc[e + 2], s3 = ssrc[e + 3];
        uint2 p = *(const uint2*)&Yl[(size_t)s0 * 256 + lane * 4];
        uint2 q = *(const uint2*)&Yl[(size_t)s1 * 256 + lane * 4];
        uint2 u = *(const uint2*)&Yl[(size_t)s2 * 256 + lane * 4];
        uint2 t = *(const uint2*)&Yl[(size_t)s3 * 256 + lane * 4];
        acc.x += (__uint_as_float(p.x << 16) + __uint_as_float(q.x << 16)) +
                 (__uint_as_float(u.x << 16) + __uint_as_float(t.x << 16));
        acc.y += (__uint_as_float(p.x & 0xFFFF0000u) + __uint_as_float(q.x & 0xFFFF0000u)) +
                 (__uint_as_float(u.x & 0xFFFF0000u) + __uint_as_float(t.x & 0xFFFF0000u));
        acc.z += (__uint_as_float(p.y << 16) + __uint_as_float(q.y << 16)) +
                 (__uint_as_float(u.y << 16) + __uint_as_float(t.y << 16));
        acc.w += (__uint_as_float(p.y & 0xFFFF0000u) + __uint_as_float(q.y & 0xFFFF0000u)) +
                 (__uint_as_float(u.y & 0xFFFF0000u) + __uint_as_float(t.y & 0xFFFF0000u));
    }
    for (; e < e1; ++e) {
        int s0 = ssrc[e];
        uint2 p = *(const uint2*)&Yl[(size_t)s0 * 256 + lane * 4];
        acc.x += __uint_as_float(p.x << 16);
        acc.y += __uint_as_float(p.x & 0xFFFF0000u);
        acc.z += __uint_as_float(p.y << 16);
        acc.w += __uint_as_float(p.y & 0xFFFF0000u);
    }
    float ic = invc[n];
    float4 b = *(const float4*)&bl0[lane * 4];
    float4 yr = *(const float4*)&Yr[(size_t)n * 256 + lane * 4];
    float hx = fmaxf(acc.x * ic + b.x + yr.x, 0.f);
    float hy = fmaxf(acc.y * ic + b.y + yr.y, 0.f);
    float hz = fmaxf(acc.z * ic + b.z + yr.z, 0.f);
    float hw = fmaxf(acc.w * ic + b.w + yr.w, 0.f);
    unsigned h0, h1, l0, l1;
    split2(hx, hy, &h0, &l0);
    split2(hz, hw, &h1, &l1);
    int t2 = n >> 4, r = n & 15;
    int kc = lane >> 3, q = (lane >> 1) & 3, ee = (lane & 1) * 4;
    size_t offH = (size_t)t2 * 4096 + kc * 512 + q * 128 + r * 8 + ee;
    *(uint2*)&Hh[offH] = make_uint2(h0, h1);
    *(uint2*)&Hl[offH] = make_uint2(l0, l1);
}

// ---------------- gemm1: [Zl bf16 | Zr fp32] = H @ Wt1^T; one wave per 16-node tile ----------------

__global__ __launch_bounds__(256) void gemm1_mfma(const unsigned short* __restrict__ Hh,
                                                  const unsigned short* __restrict__ Hl,
                                                  const unsigned short* __restrict__ Bh,
                                                  const unsigned short* __restrict__ Bl,
                                                  unsigned short* __restrict__ Zl,
                                                  float* __restrict__ Zr, int N, int numTiles) {
    int tid = threadIdx.x;
    int lane = tid & 63;
    int w = __builtin_amdgcn_readfirstlane(tid >> 6);
    int ml = lane & 15, quad = lane >> 4;
    int t = blockIdx.x * 4 + w;
    if (t >= numTiles) return;

    const unsigned short* ahp = Hh + (size_t)t * 4096 + quad * 128 + ml * 8;
    const unsigned short* alp = Hl + (size_t)t * 4096 + quad * 128 + ml * 8;

    f32x4 acc[5];
    #pragma unroll
    for (int b = 0; b < 5; ++b) acc[b] = (f32x4){0.f, 0.f, 0.f, 0.f};

    #pragma unroll
    for (int kc = 0; kc < 8; ++kc) {
        bf16x8 ah = *(const bf16x8*)&ahp[kc * 512];
        bf16x8 al = *(const bf16x8*)&alp[kc * 512];
        int ko = kc * 32 + quad * 8;
        #pragma unroll
        for (int nf = 0; nf < 5; ++nf) {
            size_t bo = (size_t)(nf * 16 + ml) * 256 + ko;
            bf16x8 bh = *(const bf16x8*)&Bh[bo];
            bf16x8 bl = *(const bf16x8*)&Bl[bo];
            acc[nf] = __builtin_amdgcn_mfma_f32_16x16x32_bf16(ah, bh, acc[nf], 0, 0, 0);
            acc[nf] = __builtin_amdgcn_mfma_f32_16x16x32_bf16(ah, bl, acc[nf], 0, 0, 0);
            acc[nf] = __builtin_amdgcn_mfma_f32_16x16x32_bf16(al, bh, acc[nf], 0, 0, 0);
        }
    }
    #pragma unroll
    for (int r = 0; r < 4; ++r) {
        int n = t * 16 + quad * 4 + r;
        if (n < N) {
            #pragma unroll
            for (int nf = 0; nf < 5; ++nf) {
                int col = nf * 16 + ml;
                if (col < 40) Zl[(size_t)n * 40 + col] = f2bf_rne(acc[nf][r]);
                else Zr[(size_t)n * 40 + (col - 40)] = acc[nf][r];
            }
        }
    }
}

// ---------------- combine1: bf16 Zl gather ----------------

__global__ __launch_bounds__(256) void combine1(const unsigned short* __restrict__ Zl,
                                                const float* __restrict__ Zr,
                                                const int* __restrict__ offs,
                                                const int* __restrict__ ssrc,
                                                const float* __restrict__ invc,
                                                const float* __restrict__ bl1,
                                                float* __restrict__ H2, int N) {
    int wv = threadIdx.x >> 6, lane = threadIdx.x & 63;
    int n = blockIdx.x * 4 + wv;
    if (n >= N) return;
    if (lane >= 40) return;
    int e0 = offs[n], e1 = offs[n + 1];
    float acc = 0.f;
    int e = e0;
    for (; e + 1 < e1; e += 2) {
        int s0 = ssrc[e], s1 = ssrc[e + 1];
        unsigned a = Zl[(size_t)s0 * 40 + lane];
        unsigned b = Zl[(size_t)s1 * 40 + lane];
        acc += __uint_as_float(a << 16) + __uint_as_float(b << 16);
    }
    if (e < e1) {
        unsigned a = Zl[(size_t)ssrc[e] * 40 + lane];
        acc += __uint_as_float(a << 16);
    }
    float v = acc * invc[n] + bl1[lane] + Zr[(size_t)n * 40 + lane];
    H2[(size_t)n * 40 + lane] = v;
}

// ---------------- W_lin pre-convert: Wb[col][k'] bf16, k' = i*48+j, K'=2304 ----------------

__global__ __launch_bounds__(256) void k_wprep(const float* __restrict__ W,
                                               unsigned short* __restrict__ Wb) {
    int idx = blockIdx.x * 256 + threadIdx.x;   // < 48*2304
    if (idx >= 48 * 2304) return;
    int col = idx / 2304;
    int kp = idx - col * 2304;
    int i = kp / 48;
    int j = kp - i * 48;
    float v = 0.f;
    if (col < 40 && i < 40 && j < 40) v = W[((size_t)(i * 40 + j)) * 40 + col];
    Wb[idx] = f2bf_rne(v);
}

// ---------------- k_final_mfma v2 ----------------

__global__ __launch_bounds__(256) void k_final_mfma(const float* __restrict__ H2,
                                                    const unsigned short* __restrict__ Wb,
                                                    const float* __restrict__ blin,
                                                    float* __restrict__ out, int N) {
    __shared__ float q_lds[64 * 52];

    int tid = threadIdx.x;
    int m0 = blockIdx.x * 64;
    int lane = tid & 63;
    int w = __builtin_amdgcn_readfirstlane(tid >> 6);
    int ml = lane & 15;
    int quad = lane >> 4;
    int row = w * 16 + ml;
    int gn = m0 + row;

    float g[40];
    float s2 = 0.f;
    #pragma unroll
    for (int q4 = 0; q4 < 10; ++q4) {
        float4 v = make_float4(0.f, 0.f, 0.f, 0.f);
        if (gn < N) v = *(const float4*)&H2[(size_t)gn * 40 + q4 * 4];
        g[q4 * 4 + 0] = v.x; g[q4 * 4 + 1] = v.y;
        g[q4 * 4 + 2] = v.z; g[q4 * 4 + 3] = v.w;
        s2 += v.x * v.x + v.y * v.y + v.z * v.z + v.w * v.w;
    }
    float aln = atanhf(fminf(fmaxf(s2, 1e-15f), 0.996f)) / fmaxf(s2, 1e-30f);

    if (quad == 0) {
        float* qw = &q_lds[row * 52];
        #pragma unroll
        for (int j4 = 0; j4 < 10; ++j4)
            *(float4*)&qw[j4 * 4] = make_float4(g[j4 * 4], g[j4 * 4 + 1],
                                                g[j4 * 4 + 2], g[j4 * 4 + 3]);
        *(float4*)&qw[40] = make_float4(0.f, 0.f, 0.f, 0.f);
        *(float4*)&qw[44] = make_float4(0.f, 0.f, 0.f, 0.f);
    }
    __syncthreads();

    const float* qrow = &q_lds[row * 52];
    int jb0 = quad * 8;
    int jb1 = (quad < 2) ? (32 + quad * 8) : (quad * 8 - 16);
    int jb2 = 16 + quad * 8;
    int ih = quad >> 1;

    f32x4 acc[3];
    #pragma unroll
    for (int c = 0; c < 3; ++c) acc[c] = (f32x4){0.f, 0.f, 0.f, 0.f};

    const unsigned short* bw = Wb + (size_t)ml * 2304 + quad * 8;

    #pragma unroll
    for (int c = 0; c < 20; ++c) {
        const int kb = c * 96;
        {
            float gi = qrow[2 * c];
            float4 ga = *(const float4*)&qrow[jb0];
            float4 gb = *(const float4*)&qrow[jb0 + 4];
            union { unsigned u[4]; bf16x8 v; } A;
            A.u[0] = pack_bf16_hu(gi * ga.x, gi * ga.y);
            A.u[1] = pack_bf16_hu(gi * ga.z, gi * ga.w);
            A.u[2] = pack_bf16_hu(gi * gb.x, gi * gb.y);
            A.u[3] = pack_bf16_hu(gi * gb.z, gi * gb.w);
            #pragma unroll
            for (int cf = 0; cf < 3; ++cf) {
                bf16x8 bf = *(const bf16x8*)&bw[(size_t)cf * 16 * 2304 + kb];
                acc[cf] = __builtin_amdgcn_mfma_f32_16x16x32_bf16(A.v, bf, acc[cf], 0, 0, 0);
            }
        }
        {
            float gi = qrow[2 * c + ih];
            float4 ga = *(const float4*)&qrow[jb1];
            float4 gb = *(const float4*)&qrow[jb1 + 4];
            union { unsigned u[4]; bf16x8 v; } A;
            A.u[0] = pack_bf16_hu(gi * ga.x, gi * ga.y);
            A.u[1] = pack_bf16_hu(gi * ga.z, gi * ga.w);
            A.u[2] = pack_bf16_hu(gi * gb.x, gi * gb.y);
            A.u[3] = pack_bf16_hu(gi * gb.z, gi * gb.w);
            #pragma unroll
            for (int cf = 0; cf < 3; ++cf) {
                bf16x8 bf = *(const bf16x8*)&bw[(size_t)cf * 16 * 2304 + kb + 32];
                acc[cf] = __builtin_amdgcn_mfma_f32_16x16x32_bf16(A.v, bf, acc[cf], 0, 0, 0);
            }
        }
        {
            float gi = qrow[2 * c + 1];
            float4 ga = *(const float4*)&qrow[jb2];
            float4 gb = *(const float4*)&qrow[jb2 + 4];
            union { unsigned u[4]; bf16x8 v; } A;
            A.u[0] = pack_bf16_hu(gi * ga.x, gi * ga.y);
            A.u[1] = pack_bf16_hu(gi * ga.z, gi * ga.w);
            A.u[2] = pack_bf16_hu(gi * gb.x, gi * gb.y);
            A.u[3] = pack_bf16_hu(gi * gb.z, gi * gb.w);
            #pragma unroll
            for (int cf = 0; cf < 3; ++cf) {
                bf16x8 bf = *(const bf16x8*)&bw[(size_t)cf * 16 * 2304 + kb + 64];
                acc[cf] = __builtin_amdgcn_mfma_f32_16x16x32_bf16(A.v, bf, acc[cf], 0, 0, 0);
            }
        }
    }

    float bcol[3];
    #pragma unroll
    for (int c = 0; c < 3; ++c) {
        int col = c * 16 + ml;
        bcol[c] = (col < 40) ? blin[col] : 0.f;
    }
    bool v2 = (ml < 8);

    #pragma unroll
    for (int r = 0; r < 4; ++r) {
        int nloc = w * 16 + quad * 4 + r;
        float al = __shfl(aln, quad * 4 + r);
        float u0 = al * acc[0][r] + bcol[0];
        float u1 = al * acc[1][r] + bcol[1];
        float u2 = v2 ? (al * acc[2][r] + bcol[2]) : 0.f;
        float un2 = u0 * u0 + u1 * u1 + u2 * u2;
        #pragma unroll
        for (int m = 1; m < 16; m <<= 1) un2 += __shfl_xor(un2, m);
        float un = fmaxf(sqrtf(un2), 1e-15f);
        float tnh = tanhf(un);
        float gma = tnh / un;
        float ps = (tnh > 0.996f) ? (0.996f / tnh) : 1.0f;
        float s = gma * ps;
        float l0 = s * u0, l1 = s * u1, l2 = s * u2;
        float mx = fmaxf(l0, l1);
        if (v2) mx = fmaxf(mx, l2);
        #pragma unroll
        for (int m = 1; m < 16; m <<= 1) mx = fmaxf(mx, __shfl_xor(mx, m));
        float se = expf(l0 - mx) + expf(l1 - mx) + (v2 ? expf(l2 - mx) : 0.f);
        #pragma unroll
        for (int m = 1; m < 16; m <<= 1) se += __shfl_xor(se, m);
        float lse = logf(se);
        int go = m0 + nloc;
        if (go < N) {
            out[(size_t)go * 40 + ml] = l0 - mx - lse;
            out[(size_t)go * 40 + 16 + ml] = l1 - mx - lse;
            if (v2) out[(size_t)go * 40 + 32 + ml] = l2 - mx - lse;
        }
    }
}

// ---------------- launch ----------------

extern "C" void kernel_launch(void* const* d_in, const int* in_sizes, int n_in,
                              void* d_out, int out_size, void* d_ws, size_t ws_size,
                              hipStream_t stream) {
    const float* x    = (const float*)d_in[0];
    const int*   ei   = (const int*)d_in[1];
    const float* Wl0  = (const float*)d_in[2];
    const float* bl0  = (const float*)d_in[3];
    const float* Wr0  = (const float*)d_in[4];
    const float* Wl1  = (const float*)d_in[5];
    const float* bl1  = (const float*)d_in[6];
    const float* Wr1  = (const float*)d_in[7];
    const float* Wlin = (const float*)d_in[8];
    const float* blin = (const float*)d_in[9];
    int N = in_sizes[0] / 256;
    int E = in_sizes[1] / 2;
    const int* src = ei;
    const int* dst = ei + E;
    int numTiles = (N + 15) / 16;

    char* ws = (char*)d_ws;
    size_t off = 0;
    auto carve = [&](size_t bytes) -> char* {
        char* p = ws + off;
        off = (off + bytes + 255) & ~(size_t)255;
        return p;
    };
    int*   deg    = (int*)carve((size_t)N * 4);
    int*   cursor = (int*)carve((size_t)N * 4);
    int*   offs   = (int*)carve((size_t)(N + 1) * 4);
    float* invc   = (float*)carve((size_t)N * 4);
    int*   bsum   = (int*)carve(1024);
    int*   ssrc   = (int*)carve((size_t)E * 4);
    unsigned short* Yl = (unsigned short*)carve((size_t)N * 256 * 2);
    float* Yr     = (float*)carve((size_t)N * 256 * 4);
    unsigned short* Hh = (unsigned short*)carve((size_t)numTiles * 4096 * 2);
    unsigned short* Hl = (unsigned short*)carve((size_t)numTiles * 4096 * 2);
    unsigned short* Zl = (unsigned short*)carve((size_t)N * 40 * 2);
    float* Zr     = (float*)carve((size_t)N * 40 * 4);
    float* H2     = (float*)carve((size_t)N * 40 * 4);
    // Wb (48*2304 bf16 = 221 KB) aliases Yr (dead after combine0)
    unsigned short* Wb = (unsigned short*)Yr;
    // split weights (606 KB) alias H2 (written only at combine1, after gemm1)
    unsigned short* Wth  = (unsigned short*)H2;
    unsigned short* Wtl  = Wth + 512 * 256;
    unsigned short* Wt1h = Wtl + 512 * 256;
    unsigned short* Wt1l = Wt1h + 80 * 256;

    int G = (N + 1023) / 1024;

    hipMemsetAsync(deg, 0, (size_t)N * 4, stream);
    hipMemsetAsync(cursor, 0, (size_t)N * 4, stream);

    k_count<<<(E + 255) / 256, 256, 0, stream>>>(dst, deg, E);
    k_scanA<<<G, 256, 0, stream>>>(deg, offs, invc, bsum, N);
    k_scanB<<<1, 64, 0, stream>>>(bsum, offs, N, G);
    k_scanC<<<G, 256, 0, stream>>>(offs, bsum, N);
    k_scatter<<<(E + 255) / 256, 256, 0, stream>>>(src, dst, offs, cursor, ssrc, E);
    k_wsplit0<<<(512 * 256) / 256, 256, 0, stream>>>(Wl0, Wr0, Wth, Wtl);
    k_wsplit1<<<(80 * 256 + 255) / 256, 256, 0, stream>>>(Wl1, Wr1, Wt1h, Wt1l);
    gemm0_mfma<<<(N + 63) / 64, 512, 0, stream>>>(x, Wth, Wtl, Yl, Yr, N);
    combine0<<<(N + 3) / 4, 256, 0, stream>>>(Yl, Yr, offs, ssrc, invc, bl0, Hh, Hl, N);
    k_wprep<<<(48 * 2304) / 256, 256, 0, stream>>>(Wlin, Wb);   // after combine0 (Yr alias)
    gemm1_mfma<<<(numTiles + 3) / 4, 256, 0, stream>>>(Hh, Hl, Wt1h, Wt1l, Zl, Zr, N, numTiles);
    combine1<<<(N + 3) / 4, 256, 0, stream>>>(Zl, Zr, offs, ssrc, invc, bl1, H2, N);
    k_final_mfma<<<(N + 63) / 64, 256, 0, stream>>>(H2, Wb, blin, (float*)d_out, N);
}